// Round 4
// baseline (133.432 us; speedup 1.0000x reference)
//
#include <hip/hip_runtime.h>

#define EDIM 256
#define HDIM 256

typedef float v2f __attribute__((ext_vector_type(2)));

__device__ __forceinline__ v2f splat2(float x) { v2f r; r.x = x; r.y = x; return r; }

__device__ __forceinline__ float waveAllSum(float v) {
  #pragma unroll
  for (int m = 32; m >= 1; m >>= 1) v += __shfl_xor(v, m, 64);
  return v;
}

// ---------------------------------------------------------------------------
// K1: six row-matmuls, 8 rows/block (grid 16x6): P/Q projections for
// rel-encode and CA/CB for corr. Biases folded: rel_b1 -> P, cor_b1 -> CB.
// ---------------------------------------------------------------------------
__global__ __launch_bounds__(256) void k_proj(
    const float* __restrict__ srcE, const float* __restrict__ tgtE,
    const float* __restrict__ relW1, const float* __restrict__ relb1,
    const float* __restrict__ corW1, const float* __restrict__ corb1,
    float* __restrict__ Ps, float* __restrict__ Qs,
    float* __restrict__ Pt, float* __restrict__ Qt,
    float* __restrict__ CA, float* __restrict__ CB)
{
  const int which = blockIdx.y;       // 0..5
  const int row0  = blockIdx.x * 8;   // 0..127 rows per 'which'
  const int h     = threadIdx.x;

  const float* A; const float* W; const float* bias; float* out;
  if (which == 0)      { A = srcE; W = relW1;              bias = relb1;   out = Ps; }
  else if (which == 1) { A = srcE; W = relW1 + EDIM*HDIM;  bias = nullptr; out = Qs; }
  else if (which == 2) { A = tgtE; W = relW1;              bias = relb1;   out = Pt; }
  else if (which == 3) { A = tgtE; W = relW1 + EDIM*HDIM;  bias = nullptr; out = Qt; }
  else if (which == 4) { A = srcE; W = corW1;              bias = nullptr; out = CA; }
  else                 { A = tgtE; W = corW1 + EDIM*HDIM;  bias = corb1;   out = CB; }

  __shared__ float arow[8][EDIM];
  #pragma unroll
  for (int r = 0; r < 8; ++r) arow[r][h] = A[(row0 + r)*EDIM + h];
  __syncthreads();

  float acc[8];
  const float init = bias ? bias[h] : 0.0f;
  #pragma unroll
  for (int r = 0; r < 8; ++r) acc[r] = init;

  for (int d = 0; d < EDIM; d += 4) {
    const float w0 = W[(d+0)*HDIM + h];
    const float w1 = W[(d+1)*HDIM + h];
    const float w2 = W[(d+2)*HDIM + h];
    const float w3 = W[(d+3)*HDIM + h];
    #pragma unroll
    for (int r = 0; r < 8; ++r) {
      const float4 av = *(const float4*)&arow[r][d];
      acc[r] = fmaf(av.x,w0, fmaf(av.y,w1, fmaf(av.z,w2, fmaf(av.w,w3, acc[r]))));
    }
  }
  #pragma unroll
  for (int r = 0; r < 8; ++r) out[(row0 + r)*HDIM + h] = acc[r];
}

// ---------------------------------------------------------------------------
// K2: fused rel-encode, 8 rows (same b,i; consecutive j) per block:
// x = P[b,i,:]+Q[b,j,:]; LN; relu; @rel_W2 + b2; mask. 8x W2 reuse.
// ---------------------------------------------------------------------------
__global__ __launch_bounds__(256) void k_encode(
    const float* __restrict__ Ps, const float* __restrict__ Qs,
    const float* __restrict__ relS, float* __restrict__ outS,
    const float* __restrict__ Pt, const float* __restrict__ Qt,
    const float* __restrict__ relT, float* __restrict__ outT,
    const float* __restrict__ g1, const float* __restrict__ be1,
    const float* __restrict__ W2, const float* __restrict__ b2)
{
  const int side = blockIdx.y;
  const float* P   = side ? Pt   : Ps;
  const float* Q   = side ? Qt   : Qs;
  const float* rel = side ? relT : relS;
  float* out       = side ? outT : outS;

  const int row0 = blockIdx.x * 8;      // [0,2048)
  const int b   = row0 >> 8;
  const int ij0 = row0 & 255;
  const int i   = ij0 >> 4;
  const int j0  = ij0 & 15;             // 8 consecutive j, same i
  const int h    = threadIdx.x;
  const int wave = threadIdx.x >> 6;
  const int lane = threadIdx.x & 63;

  const float pv = P[(b*16 + i)*HDIM + h];
  float x[8];
  #pragma unroll
  for (int r = 0; r < 8; ++r) x[r] = pv + Q[(b*16 + j0 + r)*HDIM + h];

  float s1[8], s2[8];
  #pragma unroll
  for (int r = 0; r < 8; ++r) { s1[r] = x[r]; s2[r] = x[r]*x[r]; }
  #pragma unroll
  for (int m = 32; m >= 1; m >>= 1) {
    #pragma unroll
    for (int r = 0; r < 8; ++r) {
      s1[r] += __shfl_xor(s1[r], m, 64);
      s2[r] += __shfl_xor(s2[r], m, 64);
    }
  }
  __shared__ float red[4][16];
  if (lane == 0) {
    #pragma unroll
    for (int r = 0; r < 8; ++r) { red[wave][2*r] = s1[r]; red[wave][2*r+1] = s2[r]; }
  }
  __syncthreads();

  __shared__ float rl[8][HDIM];
  #pragma unroll
  for (int r = 0; r < 8; ++r) {
    const float S1 = red[0][2*r] + red[1][2*r] + red[2][2*r] + red[3][2*r];
    const float S2 = red[0][2*r+1] + red[1][2*r+1] + red[2][2*r+1] + red[3][2*r+1];
    const float mean = S1 * (1.0f/256.0f);
    const float var  = S2 * (1.0f/256.0f) - mean*mean;
    const float rinv = rsqrtf(var + 1e-5f);
    rl[r][h] = fmaxf(fmaf((x[r] - mean)*rinv, g1[h], be1[h]), 0.0f);
  }
  __syncthreads();

  const float bb = b2[h];
  float acc[8];
  #pragma unroll
  for (int r = 0; r < 8; ++r) acc[r] = bb;

  for (int k = 0; k < HDIM; k += 4) {
    const float w0 = W2[(k+0)*HDIM + h];
    const float w1 = W2[(k+1)*HDIM + h];
    const float w2 = W2[(k+2)*HDIM + h];
    const float w3 = W2[(k+3)*HDIM + h];
    #pragma unroll
    for (int r = 0; r < 8; ++r) {
      const float4 rv = *(const float4*)&rl[r][k];
      acc[r] = fmaf(rv.x,w0, fmaf(rv.y,w1, fmaf(rv.z,w2, fmaf(rv.w,w3, acc[r]))));
    }
  }
  const float* relRow = rel + (b*16 + i)*16;
  #pragma unroll
  for (int r = 0; r < 8; ++r) {
    const float mask = (relRow[j0 + r] > 0.0f) ? 1.0f : 0.0f;
    out[(b*256 + ij0 + r)*HDIM + h] = acc[r] * mask;
  }
}

// ---------------------------------------------------------------------------
// K3: which=0: SA = src_rel @ Wa + row stats (rsS,qsS); also packs gbw.
//     which=1: TBt[b][h][t] = (tgt_rel @ Wb + map_b1)^T + row stats (rsT,qsT).
// 8 rows/block.
// ---------------------------------------------------------------------------
__global__ __launch_bounds__(256) void k_pairproj(
    const float* __restrict__ srel, const float* __restrict__ trel,
    const float* __restrict__ mapW1, const float* __restrict__ mapb1,
    const float* __restrict__ mapg, const float* __restrict__ mapbe,
    const float* __restrict__ mapW2,
    float* __restrict__ SA, float* __restrict__ TBt,
    float* __restrict__ rsS, float* __restrict__ qsS,
    float* __restrict__ rsT, float* __restrict__ qsT,
    float4* __restrict__ gbw)
{
  const int which = blockIdx.y;        // 0: SA, 1: TBt
  const int r0 = blockIdx.x * 8;       // 2048 rows
  const int h  = threadIdx.x;
  const int wave = threadIdx.x >> 6;
  const int lane = threadIdx.x & 63;

  if (which == 0 && blockIdx.x == 0)
    gbw[h] = make_float4(mapg[h], mapbe[h], mapW2[h], 0.0f);

  const float* A = which ? trel : srel;
  const float* W = which ? (mapW1 + EDIM*HDIM) : mapW1;

  __shared__ float tile[8][EDIM];
  #pragma unroll
  for (int r = 0; r < 8; ++r) tile[r][h] = A[(r0 + r)*EDIM + h];
  __syncthreads();

  float acc[8];
  const float init = which ? mapb1[h] : 0.0f;
  #pragma unroll
  for (int r = 0; r < 8; ++r) acc[r] = init;

  for (int d = 0; d < EDIM; d += 4) {
    const float w0 = W[(d+0)*HDIM + h];
    const float w1 = W[(d+1)*HDIM + h];
    const float w2 = W[(d+2)*HDIM + h];
    const float w3 = W[(d+3)*HDIM + h];
    #pragma unroll
    for (int r = 0; r < 8; ++r) {
      const float4 av = *(const float4*)&tile[r][d];
      acc[r] = fmaf(av.x,w0, fmaf(av.y,w1, fmaf(av.z,w2, fmaf(av.w,w3, acc[r]))));
    }
  }

  // per-row sum & sumsq (both sides)
  float s1[8], s2[8];
  #pragma unroll
  for (int r = 0; r < 8; ++r) { s1[r] = acc[r]; s2[r] = acc[r]*acc[r]; }
  #pragma unroll
  for (int m = 32; m >= 1; m >>= 1) {
    #pragma unroll
    for (int r = 0; r < 8; ++r) {
      s1[r] += __shfl_xor(s1[r], m, 64);
      s2[r] += __shfl_xor(s2[r], m, 64);
    }
  }
  __shared__ float red[4][16];
  if (lane == 0) {
    #pragma unroll
    for (int r = 0; r < 8; ++r) { red[wave][2*r] = s1[r]; red[wave][2*r+1] = s2[r]; }
  }

  if (which == 0) {
    #pragma unroll
    for (int r = 0; r < 8; ++r) SA[(r0 + r)*HDIM + h] = acc[r];
    __syncthreads();
    if (threadIdx.x < 16) {
      const float v = red[0][threadIdx.x] + red[1][threadIdx.x] +
                      red[2][threadIdx.x] + red[3][threadIdx.x];
      const int r = threadIdx.x >> 1;
      if (threadIdx.x & 1) qsS[r0 + r] = v; else rsS[r0 + r] = v;
    }
  } else {
    __syncthreads();                    // red ready AND tile free
    if (threadIdx.x < 16) {
      const float v = red[0][threadIdx.x] + red[1][threadIdx.x] +
                      red[2][threadIdx.x] + red[3][threadIdx.x];
      const int r = threadIdx.x >> 1;
      if (threadIdx.x & 1) qsT[r0 + r] = v; else rsT[r0 + r] = v;
    }
    #pragma unroll
    for (int r = 0; r < 8; ++r) tile[r][h] = acc[r];
    __syncthreads();
    const int b = r0 >> 8, tcol = r0 & 255;
    float* dst = TBt + (((b<<8) + h)<<8) + tcol;   // TBt[b][h][tcol..tcol+8)
    const float4 v0 = make_float4(tile[0][h], tile[1][h], tile[2][h], tile[3][h]);
    const float4 v1 = make_float4(tile[4][h], tile[5][h], tile[6][h], tile[7][h]);
    *(float4*)dst = v0;
    *(float4*)(dst + 4) = v1;
  }
}

// ---------------------------------------------------------------------------
// K4: fused scores, 512-thread blocks (8 waves).
// Blocks [0,512): mapping. Block = (b, 4 s). Wave w -> s = s0+(w>>1),
//   t-half = (w&1); lane owns t = t0+2*lane (packed float2 math, 8B loads).
//   Pass 1: cross-dot G only (row stats precomputed in k_pairproj).
//   Pass 2: LN+relu+W2-dot, packed. Zero shuffles / zero LDS in hot loops.
// Blocks [512,528): corr scores, wave = one (b,s), softmax over 16.
// map_b2 / cor_b2 cancel in softmax -> dropped.
// ---------------------------------------------------------------------------
__global__ __launch_bounds__(512) void k_scores(
    const float* __restrict__ SA, const float* __restrict__ TBt,
    const float* __restrict__ rsS, const float* __restrict__ qsS,
    const float* __restrict__ rsT, const float* __restrict__ qsT,
    const float4* __restrict__ gbw,
    const float* __restrict__ CA, const float* __restrict__ CB,
    const float* __restrict__ cW2,
    float* __restrict__ mapOut, float* __restrict__ corOut)
{
  const int wave = threadIdx.x >> 6;
  const int lane = threadIdx.x & 63;

  if (blockIdx.x >= 512) {
    // ---- corr: 16 blocks x 8 waves; wave handles one bs in [0,128) ----
    const int bs = (blockIdx.x - 512)*8 + wave;
    const int b  = bs >> 4;
    const float4 ca4 = *(const float4*)(CA + bs*HDIM + lane*4);
    const float4 w24 = *(const float4*)(cW2 + lane*4);
    float sc[16];
    #pragma unroll
    for (int t = 0; t < 16; ++t) {
      const float4 cb4 = *(const float4*)(CB + (b*16 + t)*HDIM + lane*4);
      float p = fmaxf(ca4.x + cb4.x, 0.0f)*w24.x
              + fmaxf(ca4.y + cb4.y, 0.0f)*w24.y
              + fmaxf(ca4.z + cb4.z, 0.0f)*w24.z
              + fmaxf(ca4.w + cb4.w, 0.0f)*w24.w;
      sc[t] = waveAllSum(p);
    }
    float mx = sc[0];
    #pragma unroll
    for (int t = 1; t < 16; ++t) mx = fmaxf(mx, sc[t]);
    float se = 0.0f;
    #pragma unroll
    for (int t = 0; t < 16; ++t) { sc[t] = __expf(sc[t] - mx); se += sc[t]; }
    if (lane < 16) corOut[bs*16 + lane] = sc[lane] / se;
    return;
  }

  // ---- mapping ----
  const int b    = blockIdx.x >> 6;          // 64 blocks per batch
  const int s0   = (blockIdx.x & 63) * 4;
  const int sidx = wave >> 1;                // 0..3
  const int t    = (wave & 1) * 128 + lane * 2;

  const float* TBb = TBt + (b << 16);        // [h][256]
  const int srow = (b<<8) + s0 + sidx;
  const float* sa = SA + srow*HDIM;          // wave-uniform row
  const float rs_s = rsS[srow], qs_s = qsS[srow];
  const int trow = (b<<8) + t;
  const v2f rt = *(const v2f*)&rsT[trow];
  const v2f qt = *(const v2f*)&qsT[trow];

  // pass 1: cross dot
  v2f G = {0.0f, 0.0f};
  #pragma unroll 8
  for (int h = 0; h < HDIM; ++h) {
    const v2f tb = *(const v2f*)&TBb[(h<<8) + t];
    G = __builtin_elementwise_fma(tb, splat2(sa[h]), G);
  }

  v2f al, bt;
  {
    const float c = 1.0f/256.0f;
    const v2f mean = (rt + rs_s) * c;
    const v2f e2   = (qt + qs_s + 2.0f*G) * c;
    const v2f var  = e2 - mean*mean;
    al.x = rsqrtf(var.x + 1e-5f);
    al.y = rsqrtf(var.y + 1e-5f);
    bt = -mean * al;
  }

  // pass 2: LN + relu + dot(W2)
  v2f acc = {0.0f, 0.0f};
  const v2f zero = {0.0f, 0.0f};
  #pragma unroll 4
  for (int h = 0; h < HDIM; ++h) {
    const v2f tb = *(const v2f*)&TBb[(h<<8) + t];
    const float4 c4 = gbw[h];                // {g, be, w}
    const v2f u = __builtin_elementwise_fma(tb + sa[h], al, bt);
    v2f r = __builtin_elementwise_fma(u, splat2(c4.x), splat2(c4.y));
    r = __builtin_elementwise_max(r, zero);
    acc = __builtin_elementwise_fma(r, splat2(c4.z), acc);
  }

  // softmax over t (256) for each of the 4 s
  __shared__ float sc[4][256];
  *(v2f*)&sc[sidx][t] = acc;
  __syncthreads();

  if (wave < 4) {                            // wave w -> s = s0 + w
    float v0 = sc[wave][lane];
    float v1 = sc[wave][lane + 64];
    float v2 = sc[wave][lane + 128];
    float v3 = sc[wave][lane + 192];
    float mx = fmaxf(fmaxf(v0, v1), fmaxf(v2, v3));
    #pragma unroll
    for (int m = 32; m >= 1; m >>= 1) mx = fmaxf(mx, __shfl_xor(mx, m, 64));
    const float e0 = __expf(v0 - mx), e1 = __expf(v1 - mx);
    const float e2 = __expf(v2 - mx), e3 = __expf(v3 - mx);
    const float se = waveAllSum(e0 + e1 + e2 + e3);
    const float inv = 1.0f / se;
    float* orow = mapOut + ((b<<8) + s0 + wave)*256;
    orow[lane]       = e0 * inv;
    orow[lane + 64]  = e1 * inv;
    orow[lane + 128] = e2 * inv;
    orow[lane + 192] = e3 * inv;
  }
}

extern "C" void kernel_launch(void* const* d_in, const int* in_sizes, int n_in,
                              void* d_out, int out_size, void* d_ws, size_t ws_size,
                              hipStream_t stream) {
  const float* srcE  = (const float*)d_in[0];
  const float* srcR  = (const float*)d_in[1];
  const float* tgtE  = (const float*)d_in[2];
  const float* tgtR  = (const float*)d_in[3];
  const float* relW1 = (const float*)d_in[4];
  const float* relb1 = (const float*)d_in[5];
  const float* relg1 = (const float*)d_in[6];
  const float* relbe1= (const float*)d_in[7];
  const float* relW2 = (const float*)d_in[8];
  const float* relb2 = (const float*)d_in[9];
  const float* mapW1 = (const float*)d_in[10];
  const float* mapb1 = (const float*)d_in[11];
  const float* mapg  = (const float*)d_in[12];
  const float* mapbe = (const float*)d_in[13];
  const float* mapW2 = (const float*)d_in[14];
  const float* corW1 = (const float*)d_in[16];
  const float* corb1 = (const float*)d_in[17];
  const float* corW2 = (const float*)d_in[18];

  float* ws   = (float*)d_ws;
  float* Ps   = ws;                 // 32768 each
  float* Qs   = Ps   + 32768;
  float* Pt   = Qs   + 32768;
  float* Qt   = Pt   + 32768;
  float* CA   = Qt   + 32768;
  float* CB   = CA   + 32768;
  float* srel = CB   + 32768;       // 524288 each
  float* trel = srel + 524288;
  float* SA   = trel + 524288;
  float* TBt  = SA   + 524288;

  // stats/packed aliases over Ps (dead after k_encode)
  float*  rsS = Ps;                  // 2048
  float*  qsS = Ps + 2048;           // 2048
  float*  rsT = Ps + 4096;           // 2048
  float*  qsT = Ps + 6144;           // 2048
  float4* gbw = (float4*)(Ps + 8192);// 256 float4

  float* mapOut = (float*)d_out;        // 524288
  float* corOut = mapOut + 524288;      // 2048

  k_proj<<<dim3(16, 6), 256, 0, stream>>>(srcE, tgtE, relW1, relb1, corW1, corb1,
                                          Ps, Qs, Pt, Qt, CA, CB);
  k_encode<<<dim3(256, 2), 256, 0, stream>>>(Ps, Qs, srcR, srel,
                                             Pt, Qt, tgtR, trel,
                                             relg1, relbe1, relW2, relb2);
  k_pairproj<<<dim3(256, 2), 256, 0, stream>>>(srel, trel, mapW1, mapb1,
                                               mapg, mapbe, mapW2,
                                               SA, TBt, rsS, qsS, rsT, qsT, gbw);
  k_scores<<<528, 512, 0, stream>>>(SA, TBt, rsS, qsS, rsT, qsT, gbw,
                                    CA, CB, corW2, mapOut, corOut);
}

// Round 5
// 113.163 us; speedup vs baseline: 1.1791x; 1.1791x over previous
//
#include <hip/hip_runtime.h>

#define EDIM 256
#define HDIM 256

__device__ __forceinline__ float waveAllSum(float v) {
  #pragma unroll
  for (int m = 32; m >= 1; m >>= 1) v += __shfl_xor(v, m, 64);
  return v;
}

// ---------------------------------------------------------------------------
// K1: six row-matmuls, 8 rows/block (grid 16x6): P/Q projections for
// rel-encode and CA/CB for corr. Biases folded: rel_b1 -> P, cor_b1 -> CB.
// ---------------------------------------------------------------------------
__global__ __launch_bounds__(256) void k_proj(
    const float* __restrict__ srcE, const float* __restrict__ tgtE,
    const float* __restrict__ relW1, const float* __restrict__ relb1,
    const float* __restrict__ corW1, const float* __restrict__ corb1,
    float* __restrict__ Ps, float* __restrict__ Qs,
    float* __restrict__ Pt, float* __restrict__ Qt,
    float* __restrict__ CA, float* __restrict__ CB)
{
  const int which = blockIdx.y;       // 0..5
  const int row0  = blockIdx.x * 8;   // 0..127 rows per 'which'
  const int h     = threadIdx.x;

  const float* A; const float* W; const float* bias; float* out;
  if (which == 0)      { A = srcE; W = relW1;              bias = relb1;   out = Ps; }
  else if (which == 1) { A = srcE; W = relW1 + EDIM*HDIM;  bias = nullptr; out = Qs; }
  else if (which == 2) { A = tgtE; W = relW1;              bias = relb1;   out = Pt; }
  else if (which == 3) { A = tgtE; W = relW1 + EDIM*HDIM;  bias = nullptr; out = Qt; }
  else if (which == 4) { A = srcE; W = corW1;              bias = nullptr; out = CA; }
  else                 { A = tgtE; W = corW1 + EDIM*HDIM;  bias = corb1;   out = CB; }

  __shared__ float arow[8][EDIM];
  #pragma unroll
  for (int r = 0; r < 8; ++r) arow[r][h] = A[(row0 + r)*EDIM + h];
  __syncthreads();

  float acc[8];
  const float init = bias ? bias[h] : 0.0f;
  #pragma unroll
  for (int r = 0; r < 8; ++r) acc[r] = init;

  for (int d = 0; d < EDIM; d += 4) {
    const float w0 = W[(d+0)*HDIM + h];
    const float w1 = W[(d+1)*HDIM + h];
    const float w2 = W[(d+2)*HDIM + h];
    const float w3 = W[(d+3)*HDIM + h];
    #pragma unroll
    for (int r = 0; r < 8; ++r) {
      const float4 av = *(const float4*)&arow[r][d];
      acc[r] = fmaf(av.x,w0, fmaf(av.y,w1, fmaf(av.z,w2, fmaf(av.w,w3, acc[r]))));
    }
  }
  #pragma unroll
  for (int r = 0; r < 8; ++r) out[(row0 + r)*HDIM + h] = acc[r];
}

// ---------------------------------------------------------------------------
// K2: fused rel-encode, 8 rows (same b,i; consecutive j) per block:
// x = P[b,i,:]+Q[b,j,:]; LN; relu; @rel_W2 + b2; mask. 8x W2 reuse.
// ---------------------------------------------------------------------------
__global__ __launch_bounds__(256) void k_encode(
    const float* __restrict__ Ps, const float* __restrict__ Qs,
    const float* __restrict__ relS, float* __restrict__ outS,
    const float* __restrict__ Pt, const float* __restrict__ Qt,
    const float* __restrict__ relT, float* __restrict__ outT,
    const float* __restrict__ g1, const float* __restrict__ be1,
    const float* __restrict__ W2, const float* __restrict__ b2)
{
  const int side = blockIdx.y;
  const float* P   = side ? Pt   : Ps;
  const float* Q   = side ? Qt   : Qs;
  const float* rel = side ? relT : relS;
  float* out       = side ? outT : outS;

  const int row0 = blockIdx.x * 8;      // [0,2048)
  const int b   = row0 >> 8;
  const int ij0 = row0 & 255;
  const int i   = ij0 >> 4;
  const int j0  = ij0 & 15;             // 8 consecutive j, same i
  const int h    = threadIdx.x;
  const int wave = threadIdx.x >> 6;
  const int lane = threadIdx.x & 63;

  const float pv = P[(b*16 + i)*HDIM + h];
  float x[8];
  #pragma unroll
  for (int r = 0; r < 8; ++r) x[r] = pv + Q[(b*16 + j0 + r)*HDIM + h];

  float s1[8], s2[8];
  #pragma unroll
  for (int r = 0; r < 8; ++r) { s1[r] = x[r]; s2[r] = x[r]*x[r]; }
  #pragma unroll
  for (int m = 32; m >= 1; m >>= 1) {
    #pragma unroll
    for (int r = 0; r < 8; ++r) {
      s1[r] += __shfl_xor(s1[r], m, 64);
      s2[r] += __shfl_xor(s2[r], m, 64);
    }
  }
  __shared__ float red[4][16];
  if (lane == 0) {
    #pragma unroll
    for (int r = 0; r < 8; ++r) { red[wave][2*r] = s1[r]; red[wave][2*r+1] = s2[r]; }
  }
  __syncthreads();

  __shared__ float rl[8][HDIM];
  #pragma unroll
  for (int r = 0; r < 8; ++r) {
    const float S1 = red[0][2*r] + red[1][2*r] + red[2][2*r] + red[3][2*r];
    const float S2 = red[0][2*r+1] + red[1][2*r+1] + red[2][2*r+1] + red[3][2*r+1];
    const float mean = S1 * (1.0f/256.0f);
    const float var  = S2 * (1.0f/256.0f) - mean*mean;
    const float rinv = rsqrtf(var + 1e-5f);
    rl[r][h] = fmaxf(fmaf((x[r] - mean)*rinv, g1[h], be1[h]), 0.0f);
  }
  __syncthreads();

  const float bb = b2[h];
  float acc[8];
  #pragma unroll
  for (int r = 0; r < 8; ++r) acc[r] = bb;

  for (int k = 0; k < HDIM; k += 4) {
    const float w0 = W2[(k+0)*HDIM + h];
    const float w1 = W2[(k+1)*HDIM + h];
    const float w2 = W2[(k+2)*HDIM + h];
    const float w3 = W2[(k+3)*HDIM + h];
    #pragma unroll
    for (int r = 0; r < 8; ++r) {
      const float4 rv = *(const float4*)&rl[r][k];
      acc[r] = fmaf(rv.x,w0, fmaf(rv.y,w1, fmaf(rv.z,w2, fmaf(rv.w,w3, acc[r]))));
    }
  }
  const float* relRow = rel + (b*16 + i)*16;
  #pragma unroll
  for (int r = 0; r < 8; ++r) {
    const float mask = (relRow[j0 + r] > 0.0f) ? 1.0f : 0.0f;
    out[(b*256 + ij0 + r)*HDIM + h] = acc[r] * mask;
  }
}

// ---------------------------------------------------------------------------
// K3: SAt[b][h][s] = (src_rel @ Wa)^T        + row stats (rsS,qsS)
//     TBt[b][h][t] = (tgt_rel @ Wb + b1)^T   + row stats (rsT,qsT)
// Both transposed via LDS so k_scores reads 4 s-values per uniform
// s_load_dwordx4. 8 rows/block. Also packs gbw = {g, be, W2}.
// ---------------------------------------------------------------------------
__global__ __launch_bounds__(256) void k_pairproj(
    const float* __restrict__ srel, const float* __restrict__ trel,
    const float* __restrict__ mapW1, const float* __restrict__ mapb1,
    const float* __restrict__ mapg, const float* __restrict__ mapbe,
    const float* __restrict__ mapW2,
    float* __restrict__ SAt, float* __restrict__ TBt,
    float* __restrict__ rsS, float* __restrict__ qsS,
    float* __restrict__ rsT, float* __restrict__ qsT,
    float4* __restrict__ gbw)
{
  const int which = blockIdx.y;        // 0: SAt, 1: TBt
  const int r0 = blockIdx.x * 8;       // 2048 rows
  const int h  = threadIdx.x;
  const int wave = threadIdx.x >> 6;
  const int lane = threadIdx.x & 63;

  if (which == 0 && blockIdx.x == 0)
    gbw[h] = make_float4(mapg[h], mapbe[h], mapW2[h], 0.0f);

  const float* A = which ? trel : srel;
  const float* W = which ? (mapW1 + EDIM*HDIM) : mapW1;

  __shared__ float tile[8][EDIM];
  #pragma unroll
  for (int r = 0; r < 8; ++r) tile[r][h] = A[(r0 + r)*EDIM + h];
  __syncthreads();

  float acc[8];
  const float init = which ? mapb1[h] : 0.0f;
  #pragma unroll
  for (int r = 0; r < 8; ++r) acc[r] = init;

  for (int d = 0; d < EDIM; d += 4) {
    const float w0 = W[(d+0)*HDIM + h];
    const float w1 = W[(d+1)*HDIM + h];
    const float w2 = W[(d+2)*HDIM + h];
    const float w3 = W[(d+3)*HDIM + h];
    #pragma unroll
    for (int r = 0; r < 8; ++r) {
      const float4 av = *(const float4*)&tile[r][d];
      acc[r] = fmaf(av.x,w0, fmaf(av.y,w1, fmaf(av.z,w2, fmaf(av.w,w3, acc[r]))));
    }
  }

  // per-row sum & sumsq
  float s1[8], s2[8];
  #pragma unroll
  for (int r = 0; r < 8; ++r) { s1[r] = acc[r]; s2[r] = acc[r]*acc[r]; }
  #pragma unroll
  for (int m = 32; m >= 1; m >>= 1) {
    #pragma unroll
    for (int r = 0; r < 8; ++r) {
      s1[r] += __shfl_xor(s1[r], m, 64);
      s2[r] += __shfl_xor(s2[r], m, 64);
    }
  }
  __shared__ float red[4][16];
  if (lane == 0) {
    #pragma unroll
    for (int r = 0; r < 8; ++r) { red[wave][2*r] = s1[r]; red[wave][2*r+1] = s2[r]; }
  }
  __syncthreads();                     // red ready; tile reads done

  if (threadIdx.x < 16) {
    const float v = red[0][threadIdx.x] + red[1][threadIdx.x] +
                    red[2][threadIdx.x] + red[3][threadIdx.x];
    const int r = threadIdx.x >> 1;
    float* rs = which ? rsT : rsS;
    float* qs = which ? qsT : qsS;
    if (threadIdx.x & 1) qs[r0 + r] = v; else rs[r0 + r] = v;
  }

  // transpose through LDS
  #pragma unroll
  for (int r = 0; r < 8; ++r) tile[r][h] = acc[r];
  __syncthreads();
  const int b = r0 >> 8, col = r0 & 255;
  float* dst = (which ? TBt : SAt) + (b<<16) + (h<<8) + col;
  const float4 v0 = make_float4(tile[0][h], tile[1][h], tile[2][h], tile[3][h]);
  const float4 v1 = make_float4(tile[4][h], tile[5][h], tile[6][h], tile[7][h]);
  *(float4*)dst = v0;
  *(float4*)(dst + 4) = v1;
}

// ---------------------------------------------------------------------------
// K4: fused scores, 512-thread blocks (8 waves).
// Blocks [0,512): mapping. Block = (b, 4 s). Wave = (hw, tw): tw = t-quarter
//   (lane owns t = 64*tw+lane, 4 s in registers -> 4 indep FMA chains per
//   load), hw = h-half (128 iters/wave). Partials combined via 8KB LDS.
//   SAt/gbw reads are wave-uniform s_load_dwordx4. Zero shuffles in hot loop.
// Blocks [512,528): corr scores, wave = one (b,s), softmax over 16.
// map_b2 / cor_b2 cancel in softmax -> dropped.
// ---------------------------------------------------------------------------
__global__ __launch_bounds__(512) void k_scores(
    const float* __restrict__ SAt, const float* __restrict__ TBt,
    const float* __restrict__ rsS, const float* __restrict__ qsS,
    const float* __restrict__ rsT, const float* __restrict__ qsT,
    const float4* __restrict__ gbw,
    const float* __restrict__ CA, const float* __restrict__ CB,
    const float* __restrict__ cW2,
    float* __restrict__ mapOut, float* __restrict__ corOut)
{
  const int wave = threadIdx.x >> 6;
  const int lane = threadIdx.x & 63;

  if (blockIdx.x >= 512) {
    // ---- corr: 16 blocks x 8 waves; wave handles one bs in [0,128) ----
    const int bs = (blockIdx.x - 512)*8 + wave;
    const int b  = bs >> 4;
    const float4 ca4 = *(const float4*)(CA + bs*HDIM + lane*4);
    const float4 w24 = *(const float4*)(cW2 + lane*4);
    float sc[16];
    #pragma unroll
    for (int t = 0; t < 16; ++t) {
      const float4 cb4 = *(const float4*)(CB + (b*16 + t)*HDIM + lane*4);
      float p = fmaxf(ca4.x + cb4.x, 0.0f)*w24.x
              + fmaxf(ca4.y + cb4.y, 0.0f)*w24.y
              + fmaxf(ca4.z + cb4.z, 0.0f)*w24.z
              + fmaxf(ca4.w + cb4.w, 0.0f)*w24.w;
      sc[t] = waveAllSum(p);
    }
    float mx = sc[0];
    #pragma unroll
    for (int t = 1; t < 16; ++t) mx = fmaxf(mx, sc[t]);
    float se = 0.0f;
    #pragma unroll
    for (int t = 0; t < 16; ++t) { sc[t] = __expf(sc[t] - mx); se += sc[t]; }
    if (lane < 16) corOut[bs*16 + lane] = sc[lane] / se;
    return;
  }

  // ---- mapping ----
  const int b  = blockIdx.x >> 6;            // 64 blocks per batch
  const int s0 = (blockIdx.x & 63) * 4;
  const int tw = wave & 3;                   // t-quarter
  const int hw = wave >> 2;                  // h-half
  const int t  = tw*64 + lane;
  const int h0 = hw*128;

  const float* SAb = SAt + (b<<16);          // [h][256 s]
  const float* TBb = TBt + (b<<16);          // [h][256 t]

  // pass 1: partial cross dots over this wave's h-half
  float G0 = 0.f, G1 = 0.f, G2 = 0.f, G3 = 0.f;
  #pragma unroll 4
  for (int h = h0; h < h0 + 128; ++h) {
    const float  tb = TBb[(h<<8) + t];
    const float4 sv = *(const float4*)&SAb[(h<<8) + s0];
    G0 = fmaf(sv.x, tb, G0);
    G1 = fmaf(sv.y, tb, G1);
    G2 = fmaf(sv.z, tb, G2);
    G3 = fmaf(sv.w, tb, G3);
  }

  __shared__ float pg[2][4][4][64];
  pg[hw][tw][0][lane] = G0;
  pg[hw][tw][1][lane] = G1;
  pg[hw][tw][2][lane] = G2;
  pg[hw][tw][3][lane] = G3;
  __syncthreads();

  float al[4], bt[4];
  {
    const float rt = rsT[(b<<8) + t];
    const float qt = qsT[(b<<8) + t];
    #pragma unroll
    for (int si = 0; si < 4; ++si) {
      const float Gf = pg[0][tw][si][lane] + pg[1][tw][si][lane];
      const float mean = (rsS[(b<<8) + s0 + si] + rt) * (1.0f/256.0f);
      const float e2   = (qsS[(b<<8) + s0 + si] + qt + 2.0f*Gf) * (1.0f/256.0f);
      const float rinv = rsqrtf(e2 - mean*mean + 1e-5f);
      al[si] = rinv;
      bt[si] = -mean * rinv;
    }
  }
  __syncthreads();                           // pg reuse safe

  // pass 2: partial LN + relu + dot(W2)
  float a0 = 0.f, a1 = 0.f, a2 = 0.f, a3 = 0.f;
  #pragma unroll 4
  for (int h = h0; h < h0 + 128; ++h) {
    const float  tb = TBb[(h<<8) + t];
    const float4 sv = *(const float4*)&SAb[(h<<8) + s0];
    const float4 c4 = gbw[h];                // {g, be, w}
    float u, r;
    u = fmaf(tb + sv.x, al[0], bt[0]);
    r = fmaxf(fmaf(u, c4.x, c4.y), 0.0f); a0 = fmaf(r, c4.z, a0);
    u = fmaf(tb + sv.y, al[1], bt[1]);
    r = fmaxf(fmaf(u, c4.x, c4.y), 0.0f); a1 = fmaf(r, c4.z, a1);
    u = fmaf(tb + sv.z, al[2], bt[2]);
    r = fmaxf(fmaf(u, c4.x, c4.y), 0.0f); a2 = fmaf(r, c4.z, a2);
    u = fmaf(tb + sv.w, al[3], bt[3]);
    r = fmaxf(fmaf(u, c4.x, c4.y), 0.0f); a3 = fmaf(r, c4.z, a3);
  }
  pg[hw][tw][0][lane] = a0;
  pg[hw][tw][1][lane] = a1;
  pg[hw][tw][2][lane] = a2;
  pg[hw][tw][3][lane] = a3;
  __syncthreads();

  // softmax over t (256) for each of the 4 s; wave w<4 handles s = s0 + w
  if (wave < 4) {
    float v0 = pg[0][0][wave][lane] + pg[1][0][wave][lane];
    float v1 = pg[0][1][wave][lane] + pg[1][1][wave][lane];
    float v2 = pg[0][2][wave][lane] + pg[1][2][wave][lane];
    float v3 = pg[0][3][wave][lane] + pg[1][3][wave][lane];
    float mx = fmaxf(fmaxf(v0, v1), fmaxf(v2, v3));
    #pragma unroll
    for (int m = 32; m >= 1; m >>= 1) mx = fmaxf(mx, __shfl_xor(mx, m, 64));
    const float e0 = __expf(v0 - mx), e1 = __expf(v1 - mx);
    const float e2 = __expf(v2 - mx), e3 = __expf(v3 - mx);
    const float se = waveAllSum(e0 + e1 + e2 + e3);
    const float inv = 1.0f / se;
    float* orow = mapOut + ((b<<8) + s0 + wave)*256;
    orow[lane]       = e0 * inv;
    orow[lane + 64]  = e1 * inv;
    orow[lane + 128] = e2 * inv;
    orow[lane + 192] = e3 * inv;
  }
}

extern "C" void kernel_launch(void* const* d_in, const int* in_sizes, int n_in,
                              void* d_out, int out_size, void* d_ws, size_t ws_size,
                              hipStream_t stream) {
  const float* srcE  = (const float*)d_in[0];
  const float* srcR  = (const float*)d_in[1];
  const float* tgtE  = (const float*)d_in[2];
  const float* tgtR  = (const float*)d_in[3];
  const float* relW1 = (const float*)d_in[4];
  const float* relb1 = (const float*)d_in[5];
  const float* relg1 = (const float*)d_in[6];
  const float* relbe1= (const float*)d_in[7];
  const float* relW2 = (const float*)d_in[8];
  const float* relb2 = (const float*)d_in[9];
  const float* mapW1 = (const float*)d_in[10];
  const float* mapb1 = (const float*)d_in[11];
  const float* mapg  = (const float*)d_in[12];
  const float* mapbe = (const float*)d_in[13];
  const float* mapW2 = (const float*)d_in[14];
  const float* corW1 = (const float*)d_in[16];
  const float* corb1 = (const float*)d_in[17];
  const float* corW2 = (const float*)d_in[18];

  float* ws   = (float*)d_ws;
  float* Ps   = ws;                 // 32768 each
  float* Qs   = Ps   + 32768;
  float* Pt   = Qs   + 32768;
  float* Qt   = Pt   + 32768;
  float* CA   = Qt   + 32768;
  float* CB   = CA   + 32768;
  float* srel = CB   + 32768;       // 524288 each
  float* trel = srel + 524288;
  float* SAt  = trel + 524288;
  float* TBt  = SAt  + 524288;

  // stats/packed aliases over Ps (dead after k_encode)
  float*  rsS = Ps;                  // 2048
  float*  qsS = Ps + 2048;           // 2048
  float*  rsT = Ps + 4096;           // 2048
  float*  qsT = Ps + 6144;           // 2048
  float4* gbw = (float4*)(Ps + 8192);// 256 float4

  float* mapOut = (float*)d_out;        // 524288
  float* corOut = mapOut + 524288;      // 2048

  k_proj<<<dim3(16, 6), 256, 0, stream>>>(srcE, tgtE, relW1, relb1, corW1, corb1,
                                          Ps, Qs, Pt, Qt, CA, CB);
  k_encode<<<dim3(256, 2), 256, 0, stream>>>(Ps, Qs, srcR, srel,
                                             Pt, Qt, tgtR, trel,
                                             relg1, relbe1, relW2, relb2);
  k_pairproj<<<dim3(256, 2), 256, 0, stream>>>(srel, trel, mapW1, mapb1,
                                               mapg, mapbe, mapW2,
                                               SAt, TBt, rsS, qsS, rsT, qsT, gbw);
  k_scores<<<528, 512, 0, stream>>>(SAt, TBt, rsS, qsS, rsT, qsT, gbw,
                                    CA, CB, corW2, mapOut, corOut);
}

// Round 6
// 87.494 us; speedup vs baseline: 1.5250x; 1.2934x over previous
//
#include <hip/hip_runtime.h>

#define EDIM 256
#define HDIM 256

typedef float v2f __attribute__((ext_vector_type(2)));
__device__ __forceinline__ v2f splat2(float x) { v2f r; r.x = x; r.y = x; return r; }
__device__ __forceinline__ v2f pkfma(v2f a, v2f b, v2f c) { return __builtin_elementwise_fma(a, b, c); }

__device__ __forceinline__ float waveAllSum(float v) {
  #pragma unroll
  for (int m = 32; m >= 1; m >>= 1) v += __shfl_xor(v, m, 64);
  return v;
}

// ---------------------------------------------------------------------------
// K1: six row-matmuls, 8 rows/block (grid 16x6): P/Q projections for
// rel-encode and CA/CB for corr. Biases folded: rel_b1 -> P, cor_b1 -> CB.
// ---------------------------------------------------------------------------
__global__ __launch_bounds__(256) void k_proj(
    const float* __restrict__ srcE, const float* __restrict__ tgtE,
    const float* __restrict__ relW1, const float* __restrict__ relb1,
    const float* __restrict__ corW1, const float* __restrict__ corb1,
    float* __restrict__ Ps, float* __restrict__ Qs,
    float* __restrict__ Pt, float* __restrict__ Qt,
    float* __restrict__ CA, float* __restrict__ CB)
{
  const int which = blockIdx.y;       // 0..5
  const int row0  = blockIdx.x * 8;   // 0..127 rows per 'which'
  const int h     = threadIdx.x;

  const float* A; const float* W; const float* bias; float* out;
  if (which == 0)      { A = srcE; W = relW1;              bias = relb1;   out = Ps; }
  else if (which == 1) { A = srcE; W = relW1 + EDIM*HDIM;  bias = nullptr; out = Qs; }
  else if (which == 2) { A = tgtE; W = relW1;              bias = relb1;   out = Pt; }
  else if (which == 3) { A = tgtE; W = relW1 + EDIM*HDIM;  bias = nullptr; out = Qt; }
  else if (which == 4) { A = srcE; W = corW1;              bias = nullptr; out = CA; }
  else                 { A = tgtE; W = corW1 + EDIM*HDIM;  bias = corb1;   out = CB; }

  __shared__ float arow[8][EDIM];
  #pragma unroll
  for (int r = 0; r < 8; ++r) arow[r][h] = A[(row0 + r)*EDIM + h];
  __syncthreads();

  float acc[8];
  const float init = bias ? bias[h] : 0.0f;
  #pragma unroll
  for (int r = 0; r < 8; ++r) acc[r] = init;

  for (int d = 0; d < EDIM; d += 4) {
    const float w0 = W[(d+0)*HDIM + h];
    const float w1 = W[(d+1)*HDIM + h];
    const float w2 = W[(d+2)*HDIM + h];
    const float w3 = W[(d+3)*HDIM + h];
    #pragma unroll
    for (int r = 0; r < 8; ++r) {
      const float4 av = *(const float4*)&arow[r][d];
      acc[r] = fmaf(av.x,w0, fmaf(av.y,w1, fmaf(av.z,w2, fmaf(av.w,w3, acc[r]))));
    }
  }
  #pragma unroll
  for (int r = 0; r < 8; ++r) out[(row0 + r)*HDIM + h] = acc[r];
}

// ---------------------------------------------------------------------------
// K2: fused rel-encode + pair-projection, 8 rows (same b,i; consecutive j)
// per block:
//   x = P+Q; LN; relu; @rel_W2 + b2; mask           (GEMM1, rows -> LDS)
//   side0: SAp[b][s/2][h]{2} = rows @ mapWa  + row stats (rsS,qsS)
//   side1: TB[b][t][h]       = rows @ mapWb + mapb1 + row stats (rsT,qsT)
// Also packs gbw = {mapg, mapbe, mapW2}.
// ---------------------------------------------------------------------------
__global__ __launch_bounds__(256) void k_encode(
    const float* __restrict__ Ps, const float* __restrict__ Qs,
    const float* __restrict__ relS,
    const float* __restrict__ Pt, const float* __restrict__ Qt,
    const float* __restrict__ relT,
    const float* __restrict__ g1, const float* __restrict__ be1,
    const float* __restrict__ W2, const float* __restrict__ b2,
    const float* __restrict__ mapW1, const float* __restrict__ mapb1,
    const float* __restrict__ mapg, const float* __restrict__ mapbe,
    const float* __restrict__ mapW2,
    float2* __restrict__ SAp, float* __restrict__ TB,
    float* __restrict__ rsS, float* __restrict__ qsS,
    float* __restrict__ rsT, float* __restrict__ qsT,
    float4* __restrict__ gbw)
{
  const int side = blockIdx.y;
  const float* P   = side ? Pt   : Ps;
  const float* Q   = side ? Qt   : Qs;
  const float* rel = side ? relT : relS;

  const int row0 = blockIdx.x * 8;      // [0,2048)
  const int b   = row0 >> 8;
  const int ij0 = row0 & 255;
  const int i   = ij0 >> 4;
  const int j0  = ij0 & 15;             // 8 consecutive j, same i
  const int h    = threadIdx.x;
  const int wave = threadIdx.x >> 6;
  const int lane = threadIdx.x & 63;

  if (side == 0 && blockIdx.x == 0)
    gbw[h] = make_float4(mapg[h], mapbe[h], mapW2[h], 0.0f);

  const float pv = P[(b*16 + i)*HDIM + h];
  float x[8];
  #pragma unroll
  for (int r = 0; r < 8; ++r) x[r] = pv + Q[(b*16 + j0 + r)*HDIM + h];

  // LN stats for the 8 rows
  float s1[8], s2[8];
  #pragma unroll
  for (int r = 0; r < 8; ++r) { s1[r] = x[r]; s2[r] = x[r]*x[r]; }
  #pragma unroll
  for (int m = 32; m >= 1; m >>= 1) {
    #pragma unroll
    for (int r = 0; r < 8; ++r) {
      s1[r] += __shfl_xor(s1[r], m, 64);
      s2[r] += __shfl_xor(s2[r], m, 64);
    }
  }
  __shared__ float red[4][16];
  if (lane == 0) {
    #pragma unroll
    for (int r = 0; r < 8; ++r) { red[wave][2*r] = s1[r]; red[wave][2*r+1] = s2[r]; }
  }
  __syncthreads();

  __shared__ float rl[8][HDIM];
  #pragma unroll
  for (int r = 0; r < 8; ++r) {
    const float S1 = red[0][2*r] + red[1][2*r] + red[2][2*r] + red[3][2*r];
    const float S2 = red[0][2*r+1] + red[1][2*r+1] + red[2][2*r+1] + red[3][2*r+1];
    const float mean = S1 * (1.0f/256.0f);
    const float var  = S2 * (1.0f/256.0f) - mean*mean;
    const float rinv = rsqrtf(var + 1e-5f);
    rl[r][h] = fmaxf(fmaf((x[r] - mean)*rinv, g1[h], be1[h]), 0.0f);
  }
  __syncthreads();

  // GEMM1: rows = rl @ rel_W2 + b2, then mask
  const float bb = b2[h];
  float acc[8];
  #pragma unroll
  for (int r = 0; r < 8; ++r) acc[r] = bb;
  for (int k = 0; k < HDIM; k += 4) {
    const float w0 = W2[(k+0)*HDIM + h];
    const float w1 = W2[(k+1)*HDIM + h];
    const float w2 = W2[(k+2)*HDIM + h];
    const float w3 = W2[(k+3)*HDIM + h];
    #pragma unroll
    for (int r = 0; r < 8; ++r) {
      const float4 rv = *(const float4*)&rl[r][k];
      acc[r] = fmaf(rv.x,w0, fmaf(rv.y,w1, fmaf(rv.z,w2, fmaf(rv.w,w3, acc[r]))));
    }
  }
  const float* relRow = rel + (b*16 + i)*16;
  float msk[8];
  #pragma unroll
  for (int r = 0; r < 8; ++r) msk[r] = (relRow[j0 + r] > 0.0f) ? 1.0f : 0.0f;

  __syncthreads();                      // all GEMM1 reads of rl done
  #pragma unroll
  for (int r = 0; r < 8; ++r) rl[r][h] = acc[r] * msk[r];
  __syncthreads();

  // GEMM2: out = maskedRows @ (side ? mapWb : mapWa) (+ mapb1 for side1)
  const float* W = side ? (mapW1 + EDIM*HDIM) : mapW1;
  float acc2[8];
  const float init2 = side ? mapb1[h] : 0.0f;
  #pragma unroll
  for (int r = 0; r < 8; ++r) acc2[r] = init2;
  for (int k = 0; k < HDIM; k += 4) {
    const float w0 = W[(k+0)*HDIM + h];
    const float w1 = W[(k+1)*HDIM + h];
    const float w2 = W[(k+2)*HDIM + h];
    const float w3 = W[(k+3)*HDIM + h];
    #pragma unroll
    for (int r = 0; r < 8; ++r) {
      const float4 rv = *(const float4*)&rl[r][k];
      acc2[r] = fmaf(rv.x,w0, fmaf(rv.y,w1, fmaf(rv.z,w2, fmaf(rv.w,w3, acc2[r]))));
    }
  }

  // row stats of acc2
  #pragma unroll
  for (int r = 0; r < 8; ++r) { s1[r] = acc2[r]; s2[r] = acc2[r]*acc2[r]; }
  #pragma unroll
  for (int m = 32; m >= 1; m >>= 1) {
    #pragma unroll
    for (int r = 0; r < 8; ++r) {
      s1[r] += __shfl_xor(s1[r], m, 64);
      s2[r] += __shfl_xor(s2[r], m, 64);
    }
  }
  __syncthreads();                      // red safe to rewrite
  if (lane == 0) {
    #pragma unroll
    for (int r = 0; r < 8; ++r) { red[wave][2*r] = s1[r]; red[wave][2*r+1] = s2[r]; }
  }
  __syncthreads();
  if (threadIdx.x < 16) {
    const float v = red[0][threadIdx.x] + red[1][threadIdx.x] +
                    red[2][threadIdx.x] + red[3][threadIdx.x];
    const int r = threadIdx.x >> 1;
    float* rs = side ? rsT : rsS;
    float* qs = side ? qsT : qsS;
    if (threadIdx.x & 1) qs[row0 + r] = v; else rs[row0 + r] = v;
  }

  if (side == 0) {
    // packed s-pair layout: SAp[(b*128 + sp)*256 + h] = {acc2[2k], acc2[2k+1]}
    const int spBase = (b*128 + (ij0 >> 1));
    #pragma unroll
    for (int k = 0; k < 4; ++k)
      SAp[(spBase + k)*HDIM + h] = make_float2(acc2[2*k], acc2[2*k+1]);
  } else {
    #pragma unroll
    for (int r = 0; r < 8; ++r) TB[((b<<8) + ij0 + r)*HDIM + h] = acc2[r];
  }
}

// ---------------------------------------------------------------------------
// K3: fused scores, 256-thread blocks (4 waves).
// Blocks [0,512): mapping. Block = (b, 4 s); wave = t-quarter; lane owns one
//   t ROW of TB (contiguous float4 streaming, L1-friendly). The 4 s live in
//   2 packed v2f accumulators; SA comes from the packed SAp rows at
//   wave-uniform addresses (scalar path). Softmax fused in-block.
// Blocks [512,544): corr scores, wave = one (b,s), softmax over 16.
// map_b2 / cor_b2 cancel in softmax -> dropped.
// ---------------------------------------------------------------------------
__global__ __launch_bounds__(256) void k_scores(
    const float2* __restrict__ SApf, const float* __restrict__ TB,
    const float* __restrict__ rsS, const float* __restrict__ qsS,
    const float* __restrict__ rsT, const float* __restrict__ qsT,
    const float4* __restrict__ gbw,
    const float* __restrict__ CA, const float* __restrict__ CB,
    const float* __restrict__ cW2,
    float* __restrict__ mapOut, float* __restrict__ corOut)
{
  const int wave = threadIdx.x >> 6;
  const int lane = threadIdx.x & 63;

  if (blockIdx.x >= 512) {
    // ---- corr: 32 blocks x 4 waves; wave handles one bs in [0,128) ----
    const int bs = (blockIdx.x - 512)*4 + wave;
    const int b  = bs >> 4;
    const float4 ca4 = *(const float4*)(CA + bs*HDIM + lane*4);
    const float4 w24 = *(const float4*)(cW2 + lane*4);
    float sc[16];
    #pragma unroll
    for (int t = 0; t < 16; ++t) {
      const float4 cb4 = *(const float4*)(CB + (b*16 + t)*HDIM + lane*4);
      float p = fmaxf(ca4.x + cb4.x, 0.0f)*w24.x
              + fmaxf(ca4.y + cb4.y, 0.0f)*w24.y
              + fmaxf(ca4.z + cb4.z, 0.0f)*w24.z
              + fmaxf(ca4.w + cb4.w, 0.0f)*w24.w;
      sc[t] = waveAllSum(p);
    }
    float mx = sc[0];
    #pragma unroll
    for (int t = 1; t < 16; ++t) mx = fmaxf(mx, sc[t]);
    float se = 0.0f;
    #pragma unroll
    for (int t = 0; t < 16; ++t) { sc[t] = __expf(sc[t] - mx); se += sc[t]; }
    if (lane < 16) corOut[bs*16 + lane] = sc[lane] / se;
    return;
  }

  // ---- mapping ----
  const int b  = blockIdx.x >> 6;            // 64 blocks per batch
  const int s0 = (blockIdx.x & 63) * 4;
  const int t  = (wave << 6) + lane;

  const float* tbrow = TB + ((b<<8) + t)*HDIM;          // lane-private row
  const v2f* sp0 = (const v2f*)SApf + ((b<<7) + (s0>>1))*HDIM;   // s0,s0+1
  const v2f* sp1 = sp0 + HDIM;                                    // s0+2,s0+3

  // pass 1: cross dots (packed over s-pairs)
  v2f G01 = {0.f,0.f}, G23 = {0.f,0.f};
  #pragma unroll 4
  for (int h = 0; h < HDIM; h += 4) {
    const float4 tb4 = *(const float4*)&tbrow[h];
    const v2f a0 = sp0[h],   a1 = sp0[h+1], a2 = sp0[h+2], a3 = sp0[h+3];
    const v2f c0 = sp1[h],   c1 = sp1[h+1], c2 = sp1[h+2], c3 = sp1[h+3];
    G01 = pkfma(a0, splat2(tb4.x), G01); G23 = pkfma(c0, splat2(tb4.x), G23);
    G01 = pkfma(a1, splat2(tb4.y), G01); G23 = pkfma(c1, splat2(tb4.y), G23);
    G01 = pkfma(a2, splat2(tb4.z), G01); G23 = pkfma(c2, splat2(tb4.z), G23);
    G01 = pkfma(a3, splat2(tb4.w), G01); G23 = pkfma(c3, splat2(tb4.w), G23);
  }

  v2f al01, bt01, al23, bt23;
  {
    const float rt = rsT[(b<<8) + t];
    const float qt = qsT[(b<<8) + t];
    const float Gv[4] = {G01.x, G01.y, G23.x, G23.y};
    float alv[4], btv[4];
    #pragma unroll
    for (int si = 0; si < 4; ++si) {
      const float mean = (rsS[(b<<8) + s0 + si] + rt) * (1.0f/256.0f);
      const float e2   = (qsS[(b<<8) + s0 + si] + qt + 2.0f*Gv[si]) * (1.0f/256.0f);
      const float rinv = rsqrtf(e2 - mean*mean + 1e-5f);
      alv[si] = rinv;
      btv[si] = -mean * rinv;
    }
    al01.x = alv[0]; al01.y = alv[1]; al23.x = alv[2]; al23.y = alv[3];
    bt01.x = btv[0]; bt01.y = btv[1]; bt23.x = btv[2]; bt23.y = btv[3];
  }

  // pass 2: LN + relu + dot(W2), packed over s-pairs
  v2f acc01 = {0.f,0.f}, acc23 = {0.f,0.f};
  const v2f zero = {0.f,0.f};
  #pragma unroll 2
  for (int h = 0; h < HDIM; h += 4) {
    const float4 tb4 = *(const float4*)&tbrow[h];
    const v2f a0 = sp0[h], a1 = sp0[h+1], a2 = sp0[h+2], a3 = sp0[h+3];
    const v2f c0 = sp1[h], c1 = sp1[h+1], c2 = sp1[h+2], c3 = sp1[h+3];
    const float4 q0 = gbw[h], q1 = gbw[h+1], q2 = gbw[h+2], q3 = gbw[h+3];
    v2f u, r;
    u = pkfma(a0 + splat2(tb4.x), al01, bt01);
    r = __builtin_elementwise_max(pkfma(u, splat2(q0.x), splat2(q0.y)), zero);
    acc01 = pkfma(r, splat2(q0.z), acc01);
    u = pkfma(c0 + splat2(tb4.x), al23, bt23);
    r = __builtin_elementwise_max(pkfma(u, splat2(q0.x), splat2(q0.y)), zero);
    acc23 = pkfma(r, splat2(q0.z), acc23);

    u = pkfma(a1 + splat2(tb4.y), al01, bt01);
    r = __builtin_elementwise_max(pkfma(u, splat2(q1.x), splat2(q1.y)), zero);
    acc01 = pkfma(r, splat2(q1.z), acc01);
    u = pkfma(c1 + splat2(tb4.y), al23, bt23);
    r = __builtin_elementwise_max(pkfma(u, splat2(q1.x), splat2(q1.y)), zero);
    acc23 = pkfma(r, splat2(q1.z), acc23);

    u = pkfma(a2 + splat2(tb4.z), al01, bt01);
    r = __builtin_elementwise_max(pkfma(u, splat2(q2.x), splat2(q2.y)), zero);
    acc01 = pkfma(r, splat2(q2.z), acc01);
    u = pkfma(c2 + splat2(tb4.z), al23, bt23);
    r = __builtin_elementwise_max(pkfma(u, splat2(q2.x), splat2(q2.y)), zero);
    acc23 = pkfma(r, splat2(q2.z), acc23);

    u = pkfma(a3 + splat2(tb4.w), al01, bt01);
    r = __builtin_elementwise_max(pkfma(u, splat2(q3.x), splat2(q3.y)), zero);
    acc01 = pkfma(r, splat2(q3.z), acc01);
    u = pkfma(c3 + splat2(tb4.w), al23, bt23);
    r = __builtin_elementwise_max(pkfma(u, splat2(q3.x), splat2(q3.y)), zero);
    acc23 = pkfma(r, splat2(q3.z), acc23);
  }

  // softmax over t (256) for each of the 4 s
  __shared__ float sc[4][256];
  sc[0][t] = acc01.x; sc[1][t] = acc01.y; sc[2][t] = acc23.x; sc[3][t] = acc23.y;
  __syncthreads();

  // wave w handles s = s0 + w
  float v0 = sc[wave][lane];
  float v1 = sc[wave][lane + 64];
  float v2 = sc[wave][lane + 128];
  float v3 = sc[wave][lane + 192];
  float mx = fmaxf(fmaxf(v0, v1), fmaxf(v2, v3));
  #pragma unroll
  for (int m = 32; m >= 1; m >>= 1) mx = fmaxf(mx, __shfl_xor(mx, m, 64));
  const float e0 = __expf(v0 - mx), e1 = __expf(v1 - mx);
  const float e2 = __expf(v2 - mx), e3 = __expf(v3 - mx);
  const float se = waveAllSum(e0 + e1 + e2 + e3);
  const float inv = 1.0f / se;
  float* orow = mapOut + ((b<<8) + s0 + wave)*256;
  orow[lane]       = e0 * inv;
  orow[lane + 64]  = e1 * inv;
  orow[lane + 128] = e2 * inv;
  orow[lane + 192] = e3 * inv;
}

extern "C" void kernel_launch(void* const* d_in, const int* in_sizes, int n_in,
                              void* d_out, int out_size, void* d_ws, size_t ws_size,
                              hipStream_t stream) {
  const float* srcE  = (const float*)d_in[0];
  const float* srcR  = (const float*)d_in[1];
  const float* tgtE  = (const float*)d_in[2];
  const float* tgtR  = (const float*)d_in[3];
  const float* relW1 = (const float*)d_in[4];
  const float* relb1 = (const float*)d_in[5];
  const float* relg1 = (const float*)d_in[6];
  const float* relbe1= (const float*)d_in[7];
  const float* relW2 = (const float*)d_in[8];
  const float* relb2 = (const float*)d_in[9];
  const float* mapW1 = (const float*)d_in[10];
  const float* mapb1 = (const float*)d_in[11];
  const float* mapg  = (const float*)d_in[12];
  const float* mapbe = (const float*)d_in[13];
  const float* mapW2 = (const float*)d_in[14];
  const float* corW1 = (const float*)d_in[16];
  const float* corb1 = (const float*)d_in[17];
  const float* corW2 = (const float*)d_in[18];

  float* ws   = (float*)d_ws;
  float* Ps   = ws;                 // 32768 each
  float* Qs   = Ps   + 32768;
  float* Pt   = Qs   + 32768;
  float* Qt   = Pt   + 32768;
  float* CA   = Qt   + 32768;
  float* CB   = CA   + 32768;
  float2* SAp = (float2*)(CB + 32768);          // 262144 float2 = 524288 f
  float* TB   = (float*)(SAp + 262144);         // 524288 f
  float* rsS  = TB + 524288;        // 2048
  float* qsS  = rsS + 2048;
  float* rsT  = qsS + 2048;
  float* qsT  = rsT + 2048;
  float4* gbw = (float4*)(qsT + 2048);          // 256 float4

  float* mapOut = (float*)d_out;        // 524288
  float* corOut = mapOut + 524288;      // 2048

  k_proj<<<dim3(16, 6), 256, 0, stream>>>(srcE, tgtE, relW1, relb1, corW1, corb1,
                                          Ps, Qs, Pt, Qt, CA, CB);
  k_encode<<<dim3(256, 2), 256, 0, stream>>>(Ps, Qs, srcR,
                                             Pt, Qt, tgtR,
                                             relg1, relbe1, relW2, relb2,
                                             mapW1, mapb1, mapg, mapbe, mapW2,
                                             SAp, TB, rsS, qsS, rsT, qsT, gbw);
  k_scores<<<544, 256, 0, stream>>>(SAp, TB, rsS, qsS, rsT, qsT, gbw,
                                    CA, CB, corW2, mapOut, corOut);
}